// Round 9
// baseline (64.331 us; speedup 1.0000x reference)
//
#include <hip/hip_runtime.h>

// Problem constants (from reference)
#define B_      4
#define L_      512
#define S_      100
#define NG_     19
#define GS_     5
#define VOCAB_  6
#define HID_    512
#define HPOOL_  4
#define D_      64
#define ALL_    256      // HPOOL * D
#define FIREH_  32
#define MAXDIST_ 20.0f

typedef float f32x2 __attribute__((ext_vector_type(2)));
typedef float f32x4 __attribute__((ext_vector_type(4)));

#define NROWS_  (B_ * L_)             // 2048
#define RPB_    8                     // rows per block
#define NBLK_   (NROWS_ / RPB_)       // 256 blocks = 1 per CU

// ===========================================================================
// Fully fused kernel. 256 blocks x 1024 threads, 8 rows per block.
//   prefix : stage ids (800 ints), FIRE bias (threads 800..899), attn_w;
//            recompute W2[24][512] into LDS (768 FMA/thread, ffn_w L2-hot)
//   barrier
//   phase A: 608 softmax tasks (8 rows x 19 groups x 4 pools) -> s_cw;
//            meanwhile every thread copies its w2r[24] f32x2 from LDS
//   barrier
//   phase B: thread t = (row-lane rr = t>>8, cols 2*(t&255)); 2 iterations
//            cover 8 rows; 19 pooled rows + 5 singles per row, f32x2 stores.
// Rationale: R2..R8 showed main-kernel internals are flat at ~27us; the
// untouched term is the prep kernel + launch gap. This removes both.
// ===========================================================================
__global__ __launch_bounds__(1024) void fused_kernel(
    const int*   __restrict__ ids,       // (2048,100)
    const float* __restrict__ dist,      // (100,)
    const float* __restrict__ attn_w,    // (6,4)
    const float* __restrict__ value_emb, // (6,256)
    const float* __restrict__ ffn_w,     // (256,512)
    const float* __restrict__ ffn_b,     // (512,)
    const float* __restrict__ embed_tab, // (6,512)
    const float* __restrict__ fire_c,
    const float* __restrict__ fire_w1,
    const float* __restrict__ fire_w2,
    float* __restrict__ out)             // (2048,24,512)
{
  const int blk  = blockIdx.x;           // 0..255
  const int t    = threadIdx.x;          // 0..1023
  const int row0 = blk * RPB_;

  __shared__ float s_W2[24 * HID_];               // 48 KB
  __shared__ __align__(16) float s_cw[RPB_][NG_][24];  // 14.6 KB
  __shared__ int   s_ids[RPB_ * S_];              // 3.2 KB
  __shared__ float s_bias[S_];
  __shared__ float s_aw[VOCAB_ * HPOOL_];

  // --- stage ids (coalesced), FIRE bias, attn_w ---
  if (t < RPB_ * S_) s_ids[t] = ids[row0 * S_ + t];
  if (t >= 800 && t < 900) {
    const int s = t - 800;
    const float c = fmaxf(fire_c[0], 0.f);
    const float denom = logf(fmaf(c, MAXDIST_, 1.f));
    const float rel = logf(fmaf(c, dist[s], 1.f)) / denom;
    float acc = 0.f;
#pragma unroll
    for (int i = 0; i < FIREH_; ++i) {
      const float x = rel * fire_w1[i];
      acc = fmaf(x / (1.f + __expf(-x)), fire_w2[i], acc);   // silu
    }
    s_bias[s] = acc;
  }
  if (t >= 1000) s_aw[t - 1000] = attn_w[t - 1000];          // 24 values
#pragma unroll
  for (int i = t; i < RPB_ * NG_ * 24; i += 1024) ((float*)s_cw)[i] = 0.f;

  // --- W2 recompute: thread covers col c for q = half*12 .. half*12+11 ---
  {
    const int c    = t & 511;            // column 0..511
    const int half = t >> 9;             // 0/1 (wave-uniform)
    float wacc[12];
#pragma unroll
    for (int j = 0; j < 12; ++j) wacc[j] = 0.f;
#pragma unroll
    for (int h = 0; h < HPOOL_; ++h) {
#pragma unroll 16
      for (int k = 0; k < D_; ++k) {
        const float f = ffn_w[(h * D_ + k) * HID_ + c];      // coalesced, L2-hot
        wacc[0 * 4 + h] = fmaf(value_emb[(half * 3 + 0) * ALL_ + h * D_ + k], f, wacc[0 * 4 + h]);
        wacc[1 * 4 + h] = fmaf(value_emb[(half * 3 + 1) * ALL_ + h * D_ + k], f, wacc[1 * 4 + h]);
        wacc[2 * 4 + h] = fmaf(value_emb[(half * 3 + 2) * ALL_ + h * D_ + k], f, wacc[2 * 4 + h]);
      }
    }
#pragma unroll
    for (int j = 0; j < 12; ++j)
      s_W2[(half * 12 + j) * HID_ + c] = wacc[j];
  }
  __syncthreads();

  // --- phase A: 608 softmax tasks over 8 rows ---
  if (t < RPB_ * NG_ * HPOOL_) {
    const int pr = t / 76;
    const int u  = t - pr * 76;
    const int n  = u >> 2, h = u & 3;
    int idg[GS_]; float p[GS_]; float m = -1e30f;
#pragma unroll
    for (int g = 0; g < GS_; ++g) {
      idg[g] = s_ids[pr * S_ + n * GS_ + g];
      p[g] = s_aw[idg[g] * HPOOL_ + h] + s_bias[n * GS_ + g];
      m = fmaxf(m, p[g]);
    }
    float s = 0.f;
#pragma unroll
    for (int g = 0; g < GS_; ++g) { p[g] = __expf(p[g] - m); s += p[g]; }
    const float inv = 1.f / s;
#pragma unroll
    for (int g = 0; g < GS_; ++g)
      s_cw[pr][n][idg[g] * HPOOL_ + h] += p[g] * inv;   // exclusive ownership
  }

  // --- copy w2r from LDS (overlaps phase A; independent of s_cw) ---
  const int rr = t >> 8;                 // row-lane 0..3 (wave-uniform)
  const int c2 = (t & 255) * 2;          // col base
  f32x2 w2r[24];
#pragma unroll
  for (int q = 0; q < 24; ++q)
    w2r[q] = *(const f32x2*)&s_W2[q * HID_ + c2];
  const f32x2 bb = *(const f32x2*)&ffn_b[c2];
  __syncthreads();

  // --- phase B: 2 iterations x 4 row-lanes = 8 rows ---
#pragma unroll
  for (int it = 0; it < 2; ++it) {
    const int lr = it * 4 + rr;          // local row 0..7
    float* op = out + (size_t)(row0 + lr) * 24 * HID_ + c2;

    // singles first: independent stores prime the store pipe
#pragma unroll
    for (int j = 0; j < 5; ++j) {
      const int id = s_ids[lr * S_ + NG_ * GS_ + j];
      *(f32x2*)(op + (NG_ + j) * HID_) =
          *(const f32x2*)&embed_tab[id * HID_ + c2];
    }

    for (int n = 0; n < NG_; ++n) {
      const f32x4* cw4 = (const f32x4*)s_cw[lr][n];
      f32x2 acc = bb;
#pragma unroll
      for (int k = 0; k < 6; ++k) {
        const f32x4 c = cw4[k];          // wave-uniform broadcast
        acc.x = fmaf(c.x, w2r[k * 4 + 0].x, acc.x);
        acc.y = fmaf(c.x, w2r[k * 4 + 0].y, acc.y);
        acc.x = fmaf(c.y, w2r[k * 4 + 1].x, acc.x);
        acc.y = fmaf(c.y, w2r[k * 4 + 1].y, acc.y);
        acc.x = fmaf(c.z, w2r[k * 4 + 2].x, acc.x);
        acc.y = fmaf(c.z, w2r[k * 4 + 2].y, acc.y);
        acc.x = fmaf(c.w, w2r[k * 4 + 3].x, acc.x);
        acc.y = fmaf(c.w, w2r[k * 4 + 3].y, acc.y);
      }
      *(f32x2*)(op + n * HID_) = acc;
    }
  }
}

// ---------------------------------------------------------------------------
extern "C" void kernel_launch(void* const* d_in, const int* in_sizes, int n_in,
                              void* d_out, int out_size, void* d_ws, size_t ws_size,
                              hipStream_t stream) {
  const int*   src_ids = (const int*)  d_in[0];
  const float* dist    = (const float*)d_in[1];
  const float* attn_w  = (const float*)d_in[2];
  const float* valemb  = (const float*)d_in[3];
  const float* ffn_w   = (const float*)d_in[4];
  const float* ffn_b   = (const float*)d_in[5];
  const float* emb_tab = (const float*)d_in[6];
  const float* fire_c  = (const float*)d_in[7];
  const float* fire_w1 = (const float*)d_in[8];
  const float* fire_w2 = (const float*)d_in[9];

  float* out = (float*)d_out;

  hipLaunchKernelGGL(fused_kernel, dim3(NBLK_), dim3(1024), 0, stream,
                     src_ids, dist, attn_w, valemb, ffn_w, ffn_b, emb_tab,
                     fire_c, fire_w1, fire_w2, out);
}

// Round 10
// 31.765 us; speedup vs baseline: 2.0252x; 2.0252x over previous
//
#include <hip/hip_runtime.h>

// Problem constants (from reference)
#define B_      4
#define L_      512
#define S_      100
#define NG_     19
#define GS_     5
#define VOCAB_  6
#define HID_    512
#define HPOOL_  4
#define D_      64
#define ALL_    256      // HPOOL * D
#define FIREH_  32
#define MAXDIST_ 20.0f

typedef float f32x2 __attribute__((ext_vector_type(2)));
typedef float f32x4 __attribute__((ext_vector_type(4)));

#define NROWS_  (B_ * L_)             // 2048
// ws layout (floats): [0..99] bias, [128..128+24*512) W2 (q = v*4+h major, d minor)

// ---------------------------------------------------------------------------
// K1: precompute FIRE bias (100 values) and W2[v*4+h][d] = value_emb slice @ ffn_w
// ---------------------------------------------------------------------------
__global__ __launch_bounds__(128) void prep_kernel(
    const float* __restrict__ dist,      // (100,)
    const float* __restrict__ value_emb, // (6,256)
    const float* __restrict__ ffn_w,     // (256,512)
    const float* __restrict__ fire_c,
    const float* __restrict__ fire_w1,
    const float* __restrict__ fire_w2,
    float* __restrict__ bias_out,        // ws + 0
    float* __restrict__ W2_out)          // ws + 128
{
  const int b = blockIdx.x;
  const int t = threadIdx.x;
  if (b < VOCAB_ * HPOOL_ * 4) {
    const int q   = b >> 2;            // 0..23
    const int col = (b & 3) * 128 + t; // 0..511
    const int v = q >> 2, h = q & 3;
    float acc = 0.f;
#pragma unroll
    for (int k = 0; k < D_; ++k)
      acc = fmaf(value_emb[v * ALL_ + h * D_ + k],
                 ffn_w[(h * D_ + k) * HID_ + col], acc);
    W2_out[q * HID_ + col] = acc;
  } else if (t < S_) {
    const float c = fmaxf(fire_c[0], 0.f);
    const float denom = logf(fmaf(c, MAXDIST_, 1.f));
    const float rel = logf(fmaf(c, dist[t], 1.f)) / denom;
    float acc = 0.f;
#pragma unroll
    for (int i = 0; i < FIREH_; ++i) {
      const float x = rel * fire_w1[i];
      acc = fmaf(x / (1.f + __expf(-x)), fire_w2[i], acc);   // silu
    }
    bias_out[t] = acc;
  }
}

// ---------------------------------------------------------------------------
// K2: main — R2 geometry (best known: 2048 blocks x 256 thr, 1 row/block,
// thread t -> cols 2t..2t+1) + SOFTWARE-PIPELINED phase B:
// cw loads for group n+1 are issued BEFORE the FMA chain of group n, so the
// ~120cy LDS latency hides under the 96cy FMA chain instead of serializing
// 19x per row. Two named register buffers (all static indexing).
// ---------------------------------------------------------------------------
#define FMACHAIN(CA, CB, CC, CD, CE, CF)                 \
  {                                                      \
    f32x2 acc = bb;                                      \
    acc.x = fmaf(CA.x, w2r[0].x,  acc.x);                \
    acc.y = fmaf(CA.x, w2r[0].y,  acc.y);                \
    acc.x = fmaf(CA.y, w2r[1].x,  acc.x);                \
    acc.y = fmaf(CA.y, w2r[1].y,  acc.y);                \
    acc.x = fmaf(CA.z, w2r[2].x,  acc.x);                \
    acc.y = fmaf(CA.z, w2r[2].y,  acc.y);                \
    acc.x = fmaf(CA.w, w2r[3].x,  acc.x);                \
    acc.y = fmaf(CA.w, w2r[3].y,  acc.y);                \
    acc.x = fmaf(CB.x, w2r[4].x,  acc.x);                \
    acc.y = fmaf(CB.x, w2r[4].y,  acc.y);                \
    acc.x = fmaf(CB.y, w2r[5].x,  acc.x);                \
    acc.y = fmaf(CB.y, w2r[5].y,  acc.y);                \
    acc.x = fmaf(CB.z, w2r[6].x,  acc.x);                \
    acc.y = fmaf(CB.z, w2r[6].y,  acc.y);                \
    acc.x = fmaf(CB.w, w2r[7].x,  acc.x);                \
    acc.y = fmaf(CB.w, w2r[7].y,  acc.y);                \
    acc.x = fmaf(CC.x, w2r[8].x,  acc.x);                \
    acc.y = fmaf(CC.x, w2r[8].y,  acc.y);                \
    acc.x = fmaf(CC.y, w2r[9].x,  acc.x);                \
    acc.y = fmaf(CC.y, w2r[9].y,  acc.y);                \
    acc.x = fmaf(CC.z, w2r[10].x, acc.x);                \
    acc.y = fmaf(CC.z, w2r[10].y, acc.y);                \
    acc.x = fmaf(CC.w, w2r[11].x, acc.x);                \
    acc.y = fmaf(CC.w, w2r[11].y, acc.y);                \
    acc.x = fmaf(CD.x, w2r[12].x, acc.x);                \
    acc.y = fmaf(CD.x, w2r[12].y, acc.y);                \
    acc.x = fmaf(CD.y, w2r[13].x, acc.x);                \
    acc.y = fmaf(CD.y, w2r[13].y, acc.y);                \
    acc.x = fmaf(CD.z, w2r[14].x, acc.x);                \
    acc.y = fmaf(CD.z, w2r[14].y, acc.y);                \
    acc.x = fmaf(CD.w, w2r[15].x, acc.x);                \
    acc.y = fmaf(CD.w, w2r[15].y, acc.y);                \
    acc.x = fmaf(CE.x, w2r[16].x, acc.x);                \
    acc.y = fmaf(CE.x, w2r[16].y, acc.y);                \
    acc.x = fmaf(CE.y, w2r[17].x, acc.x);                \
    acc.y = fmaf(CE.y, w2r[17].y, acc.y);                \
    acc.x = fmaf(CE.z, w2r[18].x, acc.x);                \
    acc.y = fmaf(CE.z, w2r[18].y, acc.y);                \
    acc.x = fmaf(CE.w, w2r[19].x, acc.x);                \
    acc.y = fmaf(CE.w, w2r[19].y, acc.y);                \
    acc.x = fmaf(CF.x, w2r[20].x, acc.x);                \
    acc.y = fmaf(CF.x, w2r[20].y, acc.y);                \
    acc.x = fmaf(CF.y, w2r[21].x, acc.x);                \
    acc.y = fmaf(CF.y, w2r[21].y, acc.y);                \
    acc.x = fmaf(CF.z, w2r[22].x, acc.x);                \
    acc.y = fmaf(CF.z, w2r[22].y, acc.y);                \
    acc.x = fmaf(CF.w, w2r[23].x, acc.x);                \
    acc.y = fmaf(CF.w, w2r[23].y, acc.y);                \
    *(f32x2*)(op + nn * HID_) = acc;                     \
  }

__global__ __launch_bounds__(256) void main_kernel(
    const int*   __restrict__ ids,       // (B*L, 100)
    const float* __restrict__ attn_w,    // (6,4)
    const float* __restrict__ embed_tab, // (6,512)
    const float* __restrict__ ffn_b,     // (512,)
    const float* __restrict__ bias,      // (100,) from ws
    const float* __restrict__ W2,        // (24,512) from ws
    float* __restrict__ out)             // (B*L, 24, 512)
{
  const int bl = blockIdx.x;
  const int t  = threadIdx.x;

  __shared__ int   s_ids[S_];
  __shared__ float s_bias[S_];
  __shared__ float s_aw[VOCAB_ * HPOOL_];
  __shared__ __align__(16) float s_cw[NG_][24];

  if (t < S_) s_ids[t] = ids[bl * S_ + t];
  else if (t >= 100 && t < 200) s_bias[t - 100] = bias[t - 100];
  else if (t >= 224 && t < 248) s_aw[t - 224] = attn_w[t - 224];

  // hoist W2/ffn_b loads before the barrier: latency hides under phase A
  f32x2 w2r[24];
#pragma unroll
  for (int q = 0; q < 24; ++q)
    w2r[q] = *(const f32x2*)&W2[q * HID_ + 2 * t];
  const f32x2 bb = *(const f32x2*)&ffn_b[2 * t];

#pragma unroll
  for (int i = t; i < NG_ * 24; i += 256) ((float*)s_cw)[i] = 0.f;
  __syncthreads();

  // --- phase A: 76 threads ---
  if (t < NG_ * HPOOL_) {
    const int n = t >> 2, h = t & 3;
    int idg[GS_]; float p[GS_]; float m = -1e30f;
#pragma unroll
    for (int g = 0; g < GS_; ++g) {
      idg[g] = s_ids[n * GS_ + g];
      p[g] = s_aw[idg[g] * HPOOL_ + h] + s_bias[n * GS_ + g];
      m = fmaxf(m, p[g]);
    }
    float s = 0.f;
#pragma unroll
    for (int g = 0; g < GS_; ++g) { p[g] = __expf(p[g] - m); s += p[g]; }
    const float inv = 1.f / s;
#pragma unroll
    for (int g = 0; g < GS_; ++g)
      s_cw[n][idg[g] * HPOOL_ + h] += p[g] * inv;   // exclusive ownership
  }
  __syncthreads();

  float* op = out + (size_t)bl * 24 * HID_ + 2 * t;

  // --- singles FIRST: independent stores prime the store pipe ---
#pragma unroll
  for (int j = 0; j < 5; ++j) {
    const int id = s_ids[NG_ * GS_ + j];
    *(f32x2*)(op + (NG_ + j) * HID_) =
        *(const f32x2*)&embed_tab[id * HID_ + 2 * t];
  }

  // --- phase B: 2-deep software pipeline over n ---
  // Loads for group n+1 issue BEFORE the FMA chain of group n, hiding the
  // ~120cy LDS latency under the 96cy FMA chain. All indexing static.
  const f32x4* cwb = (const f32x4*)s_cw;   // [19][6] of f32x4

  f32x4 a0 = cwb[0], a1 = cwb[1], a2 = cwb[2],
        a3 = cwb[3], a4 = cwb[4], a5 = cwb[5];

#pragma unroll
  for (int pr = 0; pr < 9; ++pr) {         // pairs (2pr, 2pr+1)
    const int nb = (2 * pr + 1) * 6;
    const f32x4 b0 = cwb[nb + 0], b1 = cwb[nb + 1], b2 = cwb[nb + 2],
                b3 = cwb[nb + 3], b4 = cwb[nb + 4], b5 = cwb[nb + 5];
    {
      const int nn = 2 * pr;
      FMACHAIN(a0, a1, a2, a3, a4, a5)
    }
    const int na = (2 * pr + 2) * 6;       // 2pr+2 <= 18 valid for pr<=8
    a0 = cwb[na + 0]; a1 = cwb[na + 1]; a2 = cwb[na + 2];
    a3 = cwb[na + 3]; a4 = cwb[na + 4]; a5 = cwb[na + 5];
    {
      const int nn = 2 * pr + 1;
      FMACHAIN(b0, b1, b2, b3, b4, b5)
    }
  }
  {
    const int nn = 18;
    FMACHAIN(a0, a1, a2, a3, a4, a5)
  }
}

// ---------------------------------------------------------------------------
extern "C" void kernel_launch(void* const* d_in, const int* in_sizes, int n_in,
                              void* d_out, int out_size, void* d_ws, size_t ws_size,
                              hipStream_t stream) {
  const int*   src_ids = (const int*)  d_in[0];
  const float* dist    = (const float*)d_in[1];
  const float* attn_w  = (const float*)d_in[2];
  const float* valemb  = (const float*)d_in[3];
  const float* ffn_w   = (const float*)d_in[4];
  const float* ffn_b   = (const float*)d_in[5];
  const float* emb_tab = (const float*)d_in[6];
  const float* fire_c  = (const float*)d_in[7];
  const float* fire_w1 = (const float*)d_in[8];
  const float* fire_w2 = (const float*)d_in[9];

  float* out  = (float*)d_out;
  float* ws   = (float*)d_ws;
  float* bias = ws;         // 100 floats
  float* W2   = ws + 128;   // 24*512 floats (16B-aligned)

  hipLaunchKernelGGL(prep_kernel, dim3(97), dim3(128), 0, stream,
                     dist, valemb, ffn_w, fire_c, fire_w1, fire_w2, bias, W2);
  hipLaunchKernelGGL(main_kernel, dim3(NROWS_), dim3(256), 0, stream,
                     src_ids, attn_w, emb_tab, ffn_b, bias, W2, out);
}